// Round 1
// 9827.585 us; speedup vs baseline: 2.7083x; 2.7083x over previous
//
#include <hip/hip_runtime.h>
#include <cstdint>
#include <cstddef>

// Problem constants
#define BB   64
#define TT   512
#define HH   500
#define G4H  2000   // 4*H
#define KPAD 512    // recurrent K padded 500 -> 512
#define TCH  64     // timesteps per phase
#define D1P  1024   // layer-1 input dim padded 1000 -> 1024
#define NBLK_DIR 125
#define WSLICE (125 * 16 * 512)   // per-dir fp16 recurrent weight slice elements
#define NPAD 2048   // gate rows padded 2000 -> 2048 for MFMA GEMM

typedef _Float16 v8h __attribute__((ext_vector_type(8)));
typedef _Float16 v4h __attribute__((ext_vector_type(4)));
typedef float    v4f __attribute__((ext_vector_type(4)));

union F16x8 {
    unsigned long long u[2];
    float4 f4;
    v8h h;
};

__device__ __forceinline__ float sigm(float x) { return 1.f / (1.f + __expf(-x)); }
__device__ __forceinline__ float tanh_fast(float x) {
    float e = __expf(2.f * x);
    return 1.f - 2.f / (e + 1.f);
}

// async global->LDS, 16B per lane. LDS dest must be wave-linear (base + lane*16).
__device__ __forceinline__ void gload_lds16(const _Float16* src, _Float16* dst) {
    __builtin_amdgcn_global_load_lds(
        (const __attribute__((address_space(1))) void*)src,
        (__attribute__((address_space(3))) void*)dst, 16, 0, 0);
}

// ---- prep: W_hh [2000][500] fp32 -> fp16 MFMA-friendly slices (unchanged) ----
__global__ __launch_bounds__(256) void pad_whh16_kernel(
    const float* __restrict__ w0, const float* __restrict__ w1,
    const float* __restrict__ w2, const float* __restrict__ w3,
    _Float16* __restrict__ dst)
{
    int idx = blockIdx.x * 256 + threadIdx.x;   // exactly 4*125*16*512 threads
    int k = idx & 511;
    int t = idx >> 9;
    int n = t & 15;  t >>= 4;
    int bi = t % 125;
    int ld = t / 125;
    int g = n >> 2, j = n & 3;
    const float* src = (ld == 0) ? w0 : (ld == 1) ? w1 : (ld == 2) ? w2 : w3;
    float val = (k < HH) ? src[(g * HH + bi * 4 + j) * HH + k] : 0.f;
    dst[idx] = (_Float16)val;
}

// ---- prep: W_ih [2000][ksrc] fp32 -> fp16 padded [2][NPAD][1<<kshift] ----
__global__ __launch_bounds__(256) void pad_wih16_kernel(
    const float* __restrict__ wf, const float* __restrict__ wb,
    _Float16* __restrict__ dst, int ksrc, int kshift)
{
    int idx = blockIdx.x * 256 + threadIdx.x;
    int kdst = 1 << kshift;
    int k = idx & (kdst - 1);
    int n = (idx >> kshift) & (NPAD - 1);
    int dir = idx >> (kshift + 11);
    const float* src = dir ? wb : wf;
    float v = (n < G4H && k < ksrc) ? src[(size_t)n * ksrc + k] : 0.f;
    dst[idx] = (_Float16)v;
}

// ---- prep: seqs fp32 -> fp16 (4 elems/thread) ----
__global__ __launch_bounds__(256) void f32to16x4_kernel(
    const float* __restrict__ src, _Float16* __restrict__ dst)
{
    int idx = blockIdx.x * 256 + threadIdx.x;
    float4 v = ((const float4*)src)[idx];
    v4h o;
    o[0] = (_Float16)v.x; o[1] = (_Float16)v.y;
    o[2] = (_Float16)v.z; o[3] = (_Float16)v.w;
    ((v4h*)dst)[idx] = o;
}

// ---- MFMA input-projection GEMM for one 64-timestep chunk, both dirs ----
// gates[dir][b][tl][n] = sum_k A16[b][t0+tl][k] * W16[dir][n][k] + bias[n]
// Tile 128x128 (M spans 2 batches x 64 contiguous timesteps), BK=64.
// 4 waves (2x2), each computes 64x64 = 4x4 fragments of 16x16x32_f16.
// Staging: global_load_lds w16, linear LDS dest, XOR-swizzled SOURCE k-offset;
// ds_read_b128 applies the same XOR -> 2-way bank aliasing (free).
#define BM 128
#define BN 128
#define BKG 64

__global__ __launch_bounds__(256, 2) void gemm16_kernel(
    const _Float16* __restrict__ A16, int K,
    const _Float16* __restrict__ W16,     // [2][NPAD][K]
    const float* __restrict__ bf_, const float* __restrict__ bb_,
    float* __restrict__ gates, int t0f, int t0b)
{
    const int dir = blockIdx.z;
    const int t0  = dir ? t0b : t0f;
    const _Float16* W = W16 + (size_t)dir * NPAD * K;
    const float* bias = dir ? bb_ : bf_;
    const int mtile = blockIdx.x;     // 0..31
    const int ntile = blockIdx.y;     // 0..15
    const int tid  = threadIdx.x;
    const int lane = tid & 63;
    const int wv = __builtin_amdgcn_readfirstlane(tid >> 6);
    const int wm = wv >> 1, wn = wv & 1;

    __shared__ _Float16 Asm[BM * BKG];   // 16 KB
    __shared__ _Float16 Bsm[BN * BKG];   // 16 KB

    // Per-thread staging sources. slot s = tid + it*256 covers the tile
    // linearly: row = s>>3, slot8 = s&7. Content at (row,slot8) is
    // A[row][k0 + ((slot8 ^ (row&7))*8)..+8]  (inverse swizzle on source).
    const _Float16* aPtr[4];
    const _Float16* bPtr[4];
    #pragma unroll
    for (int it = 0; it < 4; ++it) {
        const int s = tid + it * 256;
        const int row = s >> 3;
        const int kswz = ((s ^ row) & 7) << 3;       // (slot8 ^ (row&7)) * 8
        const int rg = mtile * BM + row;
        const int b = rg >> 6;
        const int t = t0 + (rg & 63);
        aPtr[it] = A16 + (size_t)(b * TT + t) * K + kswz;
        bPtr[it] = W + (size_t)(ntile * BN + row) * K + kswz;
    }

    v4f acc[4][4];
    #pragma unroll
    for (int mt = 0; mt < 4; ++mt)
        #pragma unroll
        for (int nt = 0; nt < 4; ++nt) acc[mt][nt] = (v4f)(0.f);

    for (int k0 = 0; k0 < K; k0 += BKG) {
        #pragma unroll
        for (int it = 0; it < 4; ++it) {
            gload_lds16(aPtr[it] + k0, &Asm[(tid + it * 256) * 8]);
            gload_lds16(bPtr[it] + k0, &Bsm[(tid + it * 256) * 8]);
        }
        __syncthreads();   // drains vmcnt -> LDS tiles ready
        #pragma unroll
        for (int kk = 0; kk < 2; ++kk) {
            v8h af[4], bw[4];
            #pragma unroll
            for (int mt = 0; mt < 4; ++mt) {
                const int row = wm * 64 + mt * 16 + (lane & 15);
                const int slot = (kk * 4 + (lane >> 4)) ^ (row & 7);
                af[mt] = *(const v8h*)&Asm[row * BKG + slot * 8];
            }
            #pragma unroll
            for (int nt = 0; nt < 4; ++nt) {
                const int row = wn * 64 + nt * 16 + (lane & 15);
                const int slot = (kk * 4 + (lane >> 4)) ^ (row & 7);
                bw[nt] = *(const v8h*)&Bsm[row * BKG + slot * 8];
            }
            #pragma unroll
            for (int mt = 0; mt < 4; ++mt)
                #pragma unroll
                for (int nt = 0; nt < 4; ++nt)
                    acc[mt][nt] = __builtin_amdgcn_mfma_f32_16x16x32_f16(
                        af[mt], bw[nt], acc[mt][nt], 0, 0, 0);
        }
        __syncthreads();   // reads done before next-iter staging overwrites
    }

    // epilogue: D frag (16x16): col = lane&15, row = (lane>>4)*4 + i
    float* gout = gates + (size_t)dir * (BB * TCH * G4H);
    const int colBase = ntile * BN + wn * 64 + (lane & 15);
    const int rowBase = mtile * BM + wm * 64 + ((lane >> 4) * 4);
    #pragma unroll
    for (int nt = 0; nt < 4; ++nt) {
        const int n = colBase + nt * 16;
        if (n < G4H) {
            const float bv = bias[n];
            #pragma unroll
            for (int mt = 0; mt < 4; ++mt) {
                const int r = rowBase + mt * 16;
                const int b = r >> 6;
                const int tl = r & 63;        // rows r..r+3 stay in same batch
                float* gp = gout + (size_t)(b * TCH + tl) * G4H + n;
                #pragma unroll
                for (int i = 0; i < 4; ++i)
                    gp[(size_t)i * G4H] = acc[mt][nt][i] + bv;
            }
        }
    }
}

// ---- persistent MFMA recurrence: one launch = 64 timesteps, both dirs ----
// (unchanged except: y output may be fp16 [layer 0 -> padded out16 buffer]
//  or fp32 [layer 1 -> d_out])
__global__ __launch_bounds__(256, 1) void lstm_phase_kernel(
    const float*    __restrict__ gates,   // [dir][B][TCH][G4H]
    const _Float16* __restrict__ whh16,   // layer base: [dir][bi][16][512]
    const int*      __restrict__ lengths,
    _Float16* __restrict__ h16,           // [dir][2][B][512] fp16
    float*    __restrict__ cbuf,          // [dir][B][KPAD] fp32
    void*     __restrict__ yout, int y_ld, int yF16,
    int s0, unsigned int tgt0,
    unsigned int* __restrict__ barrier)
{
    const int tid  = threadIdx.x;
    const int dir  = (blockIdx.x >= NBLK_DIR) ? 1 : 0;
    const int bi   = blockIdx.x - dir * NBLK_DIR;
    const int u0   = bi * 4;
    const int lane = tid & 63;
    const int kc   = __builtin_amdgcn_readfirstlane(tid >> 6);  // k-quarter

    __shared__ float redC[4][4][16][17];        // [kc][mt][m][n] (+1 pad)
    __shared__ float ch[2][4][64];              // [c/h fp32][j][b]
    __shared__ unsigned short hsh[4][64];       // fp16 bits of new h [j][b]

    // B fragments: W slice rows n=lane&15, k = kc*128 + kt*32 + (lane>>4)*8 + j
    v8h bfr[4];
    {
        const _Float16* wbase = whh16 + (size_t)dir * WSLICE
            + ((size_t)bi * 16 + (lane & 15)) * 512 + kc * 128 + ((lane >> 4) * 8);
        #pragma unroll
        for (int kt = 0; kt < 4; ++kt) {
            F16x8 f; f.f4 = *(const float4*)(wbase + kt * 32);
            bfr[kt] = f.h;
        }
    }

    // epilogue identity: thread = (batch eb, unit j)
    const int eb = tid >> 2;
    const int ej = tid & 3;
    const int len_r = lengths[eb];

    ch[0][ej][eb] = cbuf[(size_t)(dir * BB + eb) * KPAD + u0 + ej];
    ch[1][ej][eb] = (float)h16[((size_t)(dir * 2 + 0) * BB + eb) * 512 + u0 + ej];
    __syncthreads();

    const float* gbase = gates + (size_t)dir * (BB * TCH * G4H);
    unsigned int* cnt = barrier + dir;

    for (int sl = 0; sl < TCH; ++sl) {
        const int s   = s0 + sl;
        const int par = s & 1;
        const int t   = dir ? (TT - 1 - s) : s;
        const int tl  = dir ? (TCH - 1 - sl) : sl;

        // gate-x prefetch (fp32, plain)
        float gxv[4];
        {
            const float* gx = gbase + ((size_t)eb * TCH + tl) * G4H + u0 + ej;
            #pragma unroll
            for (int g = 0; g < 4; ++g) gxv[g] = gx[g * HH];
        }

        // A fragments via coherent b64 atomic loads
        F16x8 av[4][4];
        {
            const char* habase = (const char*)(h16 + (size_t)(dir * 2 + par) * BB * 512);
            const int rowoff = (lane & 15) * 512 + kc * 128 + ((lane >> 4) * 8);
            #pragma unroll
            for (int mt = 0; mt < 4; ++mt) {
                #pragma unroll
                for (int kt = 0; kt < 4; ++kt) {
                    const size_t off = ((size_t)(mt * 16) * 512 + rowoff + kt * 32) * 2;
                    const unsigned long long* p = (const unsigned long long*)(habase + off);
                    av[mt][kt].u[0] = __hip_atomic_load(p,     __ATOMIC_RELAXED, __HIP_MEMORY_SCOPE_AGENT);
                    av[mt][kt].u[1] = __hip_atomic_load(p + 1, __ATOMIC_RELAXED, __HIP_MEMORY_SCOPE_AGENT);
                }
            }
        }

        // 16 MFMAs: 4 independent acc chains (mt), depth 4 (kt)
        v4f acc[4];
        #pragma unroll
        for (int mt = 0; mt < 4; ++mt) acc[mt] = (v4f)(0.f);
        #pragma unroll
        for (int kt = 0; kt < 4; ++kt) {
            #pragma unroll
            for (int mt = 0; mt < 4; ++mt) {
                acc[mt] = __builtin_amdgcn_mfma_f32_16x16x32_f16(
                    av[mt][kt].h, bfr[kt], acc[mt], 0, 0, 0);
            }
        }

        // k-split partial C tiles -> LDS  (D: m=(lane>>4)*4+i, n=lane&15)
        #pragma unroll
        for (int mt = 0; mt < 4; ++mt) {
            #pragma unroll
            for (int i = 0; i < 4; ++i)
                redC[kc][mt][(lane >> 4) * 4 + i][lane & 15] = acc[mt][i];
        }
        __syncthreads();

        // epilogue: thread owns (batch eb, unit j)
        {
            const int mt = eb >> 4, m = eb & 15;
            float pre[4];
            #pragma unroll
            for (int g = 0; g < 4; ++g) {
                const int n = g * 4 + ej;
                pre[g] = (redC[0][mt][m][n] + redC[1][mt][m][n])
                       + (redC[2][mt][m][n] + redC[3][mt][m][n]) + gxv[g];
            }
            const float cold = ch[0][ej][eb];
            const float hold = ch[1][ej][eb];
            const float ig = sigm(pre[0]);
            const float fg = sigm(pre[1]);
            const float gg = tanh_fast(pre[2]);
            const float og = sigm(pre[3]);
            const float cn = fg * cold + ig * gg;
            const float hn = og * tanh_fast(cn);
            const bool msk = (t < len_r);
            const float cw = msk ? cn : cold;
            const float hw = msk ? hn : hold;
            ch[0][ej][eb] = cw;
            ch[1][ej][eb] = hw;
            const _Float16 hw16 = (_Float16)hw;
            hsh[ej][eb] = *(const unsigned short*)&hw16;
            const size_t yoff = ((size_t)eb * TT + t) * y_ld + dir * HH + u0 + ej;
            if (yF16) ((_Float16*)yout)[yoff] = (_Float16)(msk ? hn : 0.f);
            else      ((float*)yout)[yoff]    = msk ? hn : 0.f;
        }
        __syncthreads();   // hsh ready; redC reads done

        // publish h as fp16 pairs (coherent b32 stores), even-j threads only
        if ((ej & 1) == 0) {
            const unsigned int pk = (unsigned int)hsh[ej][eb]
                                  | ((unsigned int)hsh[ej + 1][eb] << 16);
            unsigned int* dst = (unsigned int*)
                (h16 + ((size_t)(dir * 2 + (par ^ 1)) * BB + eb) * 512 + u0 + ej);
            __hip_atomic_store(dst, pk, __ATOMIC_RELAXED, __HIP_MEMORY_SCOPE_AGENT);
        }

        __syncthreads();
        if (tid == 0) {
            __hip_atomic_fetch_add(cnt, 1u, __ATOMIC_RELAXED, __HIP_MEMORY_SCOPE_AGENT);
            const unsigned int tgt = tgt0 + (unsigned int)(sl + 1) * NBLK_DIR;
            while (__hip_atomic_load(cnt, __ATOMIC_RELAXED, __HIP_MEMORY_SCOPE_AGENT) < tgt) {
                __builtin_amdgcn_s_sleep(8);
            }
        }
        __syncthreads();
    }

    // persist c (fp32) for next phase
    cbuf[(size_t)(dir * BB + eb) * KPAD + u0 + ej] = ch[0][ej][eb];
}

extern "C" void kernel_launch(void* const* d_in, const int* in_sizes, int n_in,
                              void* d_out, int out_size, void* d_ws, size_t ws_size,
                              hipStream_t stream)
{
    (void)in_sizes; (void)n_in; (void)out_size; (void)ws_size;

    const float* seqs    = (const float*)d_in[0];
    const int*   lengths = (const int*)  d_in[1];
    const float* W_ih0f  = (const float*)d_in[2];
    const float* W_hh0f  = (const float*)d_in[3];
    const float* b0f     = (const float*)d_in[4];
    const float* W_ih0b  = (const float*)d_in[5];
    const float* W_hh0b  = (const float*)d_in[6];
    const float* b0b     = (const float*)d_in[7];
    const float* W_ih1f  = (const float*)d_in[8];
    const float* W_hh1f  = (const float*)d_in[9];
    const float* b1f     = (const float*)d_in[10];
    const float* W_ih1b  = (const float*)d_in[11];
    const float* W_hh1b  = (const float*)d_in[12];
    const float* b1b     = (const float*)d_in[13];

    char* ws = (char*)d_ws;
    const size_t SZ_GATES = (size_t)2 * BB * TCH * G4H * 4;   //  65,536,000
    const size_t SZ_SEQ16 = (size_t)BB * TT * 512 * 2;        //  33,554,432
    const size_t SZ_OUT16 = (size_t)BB * TT * D1P * 2;        //  67,108,864
    const size_t SZ_WIH0  = (size_t)2 * NPAD * 512 * 2;       //   4,194,304
    const size_t SZ_WIH1  = (size_t)2 * NPAD * D1P * 2;       //   8,388,608
    const size_t SZ_WHH16 = (size_t)4 * WSLICE * 2;           //   8,192,000
    const size_t SZ_H16   = (size_t)2 * 2 * BB * 512 * 2;     //     262,144
    const size_t SZ_CBUF  = (size_t)2 * BB * KPAD * 4;        //     262,144

    size_t off = 0;
    float*     gatesc = (float*)(ws + off);     off += SZ_GATES;
    _Float16*  seq16  = (_Float16*)(ws + off);  off += SZ_SEQ16;
    _Float16*  out16  = (_Float16*)(ws + off);  off += SZ_OUT16;
    _Float16*  wih016 = (_Float16*)(ws + off);  off += SZ_WIH0;
    _Float16*  wih116 = (_Float16*)(ws + off);  off += SZ_WIH1;
    _Float16*  whh16  = (_Float16*)(ws + off);  off += SZ_WHH16;
    _Float16*  h16    = (_Float16*)(ws + off);  off += SZ_H16;
    float*     cbuf   = (float*)(ws + off);     off += SZ_CBUF;
    unsigned int* barrier = (unsigned int*)(ws + off);

    // one-time prep
    pad_whh16_kernel<<<16000, 256, 0, stream>>>(W_hh0f, W_hh0b, W_hh1f, W_hh1b, whh16);
    pad_wih16_kernel<<<8192,  256, 0, stream>>>(W_ih0f, W_ih0b, wih016, 512, 9);
    pad_wih16_kernel<<<16384, 256, 0, stream>>>(W_ih1f, W_ih1b, wih116, 1000, 10);
    f32to16x4_kernel<<<16384, 256, 0, stream>>>(seqs, seq16);
    hipMemsetAsync(out16, 0, SZ_OUT16, stream);   // zeros k-pad cols 1000..1023
    hipMemsetAsync(barrier, 0, 2 * sizeof(unsigned int), stream);

    for (int layer = 0; layer < 2; ++layer) {
        hipMemsetAsync(h16, 0, SZ_H16, stream);
        hipMemsetAsync(cbuf, 0, SZ_CBUF, stream);

        const _Float16* A16  = layer ? out16 : seq16;
        const int       K    = layer ? D1P : 512;
        const _Float16* WL   = layer ? wih116 : wih016;
        const float*    bf_  = layer ? b1f : b0f;
        const float*    bb_  = layer ? b1b : b0b;
        const _Float16* whhL = whh16 + (size_t)layer * 2 * WSLICE;
        void*           yo   = layer ? d_out : (void*)out16;
        const int       y_ld = layer ? 1000 : D1P;
        const int       yF16 = layer ? 0 : 1;

        for (int ph = 0; ph < 8; ++ph) {
            const int t0f = ph * TCH;
            const int t0b = TT - TCH * (ph + 1);
            gemm16_kernel<<<dim3(32, 16, 2), 256, 0, stream>>>(
                A16, K, WL, bf_, bb_, gatesc, t0f, t0b);
            const unsigned int tgt0 = (unsigned int)(layer * TT + ph * TCH) * NBLK_DIR;
            lstm_phase_kernel<<<2 * NBLK_DIR, 256, 0, stream>>>(
                gatesc, whhL, lengths, h16, cbuf, yo, y_ld, yF16,
                ph * TCH, tgt0, barrier);
        }
    }
}